// Round 1
// baseline (478.900 us; speedup 1.0000x reference)
//
#include <hip/hip_runtime.h>

#define B   256
#define T   256
#define S   20
#define U1  32
#define G1  128   // 4*U1
#define U2  24
#define G2  96    // 4*U2

__device__ __forceinline__ float fast_rcp(float x) { return __builtin_amdgcn_rcpf(x); }
__device__ __forceinline__ float sigmoidf_(float x) { return fast_rcp(1.0f + __expf(-x)); }
// tanh(x) = 1 - 2/(1+e^{2x}); saturates correctly at +-1 for large |x|
__device__ __forceinline__ float tanhf_fast(float x) { return 1.0f - 2.0f * fast_rcp(1.0f + __expf(2.0f * x)); }

// Inner LSTM: one thread per (b,t) row. h/c/z all in VGPRs; Ui/Wi/bi are
// wave-uniform -> compiler emits s_load (scalar cache), v_fma with SGPR operand.
// WRITE_P=true: emit P row = bo + h @ Wo (96 floats); else emit feats (32 floats).
template <bool WRITE_P>
__global__ __launch_bounds__(256, 1) void inner_kernel(
    const float* __restrict__ x,        // [B*T*S]
    const int*   __restrict__ lengths,  // [B]
    const float* __restrict__ Wi,       // [G1]    (D=1)
    const float* __restrict__ Ui,       // [U1*G1]
    const float* __restrict__ bi,       // [G1]
    const float* __restrict__ Wo,       // [U1*G2]
    const float* __restrict__ bo,       // [G2]
    float* __restrict__ outbuf)         // [B*T*G2] or [B*T*U1]
{
    const int r = blockIdx.x * 256 + threadIdx.x;   // row = b*T + t
    const int t = r & (T - 1);
    const int b = r >> 8;
    if (t >= lengths[b]) return;   // masked step: its output is never read

    // load this row's 20 scalar inputs up front (5x dwordx4, 16B-aligned)
    float xr[S];
    const float* xp = x + (size_t)r * S;
#pragma unroll
    for (int s = 0; s < S; ++s) xr[s] = xp[s];

    float h[U1], c[U1];
#pragma unroll
    for (int u = 0; u < U1; ++u) { h[u] = 0.0f; c[u] = 0.0f; }

#pragma unroll 1
    for (int s = 0; s < S; ++s) {
        float z[G1];
        const float xv = xr[s];
#pragma unroll
        for (int j = 0; j < G1; ++j) z[j] = bi[j] + xv * Wi[j];
        if (s > 0) {   // h==0 on step 0: skip 4096 wasted FMAs (uniform branch)
#pragma unroll
            for (int k = 0; k < U1; ++k) {
                const float hk = h[k];
                const float* Urow = Ui + k * G1;
#pragma unroll
                for (int j = 0; j < G1; ++j) z[j] += hk * Urow[j];
            }
        }
#pragma unroll
        for (int u = 0; u < U1; ++u) {
            const float ig = sigmoidf_(z[u]);
            const float fg = sigmoidf_(z[U1 + u]);
            const float gg = tanhf_fast(z[2 * U1 + u]);
            const float og = sigmoidf_(z[3 * U1 + u]);
            const float cn = fg * c[u] + ig * gg;
            c[u] = cn;
            h[u] = og * tanhf_fast(cn);
        }
    }

    if constexpr (WRITE_P) {
        // P row = bo + h @ Wo   (folds the outer LSTM's input matmul in here,
        // where we have 1024 waves of parallelism instead of 4)
        float p[G2];
#pragma unroll
        for (int j = 0; j < G2; ++j) p[j] = bo[j];
#pragma unroll
        for (int k = 0; k < U1; ++k) {
            const float hk = h[k];
            const float* Wrow = Wo + k * G2;
#pragma unroll
            for (int j = 0; j < G2; ++j) p[j] += hk * Wrow[j];
        }
        float4* Pp = (float4*)(outbuf + (size_t)r * G2);
#pragma unroll
        for (int j = 0; j < G2 / 4; ++j)
            Pp[j] = make_float4(p[4 * j], p[4 * j + 1], p[4 * j + 2], p[4 * j + 3]);
    } else {
        float4* Fp = (float4*)(outbuf + (size_t)r * U1);
#pragma unroll
        for (int j = 0; j < U1 / 4; ++j)
            Fp[j] = make_float4(h[4 * j], h[4 * j + 1], h[4 * j + 2], h[4 * j + 3]);
    }
}

// Outer LSTM + dense head: one 64-thread block (1 wave) per sequence b.
// Lane u < 24 owns unit u: computes all 4 of its gate pre-activations
// (weights Uo held in VGPRs), updates c/h locally; h broadcast via
// double-buffered LDS (same-address reads = free broadcast), 1 barrier/step.
template <bool USE_P>
__global__ __launch_bounds__(64, 1) void outer_kernel(
    const float* __restrict__ buf,      // P [B*T*G2] or feats [B*T*U1]
    const int*   __restrict__ lengths,  // [B]
    const float* __restrict__ Wo,       // [U1*G2] (only if !USE_P)
    const float* __restrict__ Uo,       // [U2*G2]
    const float* __restrict__ bo,       // [G2]    (only if !USE_P)
    const float* __restrict__ Wd,       // [U2]
    const float* __restrict__ bd,       // [1]
    float* __restrict__ out)            // [B]
{
    const int b = blockIdx.x;
    const int lane = threadIdx.x;
    const int u = (lane < U2) ? lane : 0;
    __shared__ __align__(16) float hs[2][U2];

    // recurrent weights for my unit's 4 gates: wu[g][k] = Uo[k][g*U2+u]
    float wu[4][U2];
#pragma unroll
    for (int g = 0; g < 4; ++g)
#pragma unroll
        for (int k = 0; k < U2; ++k)
            wu[g][k] = Uo[k * G2 + g * U2 + u];

    float wx[4][U1];
    float bz[4];
    if constexpr (!USE_P) {
#pragma unroll
        for (int g = 0; g < 4; ++g) {
            bz[g] = bo[g * U2 + u];
#pragma unroll
            for (int k = 0; k < U1; ++k)
                wx[g][k] = Wo[k * G2 + g * U2 + u];
        }
    }

    if (lane < U2) hs[0][lane] = 0.0f;
    __syncthreads();

    const int len = lengths[b];          // >= 1 by construction
    const int rowstride = USE_P ? G2 : U1;
    const float* Pb = buf + (size_t)b * T * rowstride;

    float cu = 0.0f, hu = 0.0f;
    int p = 0;

    // prefetch t=0 inputs
    float pt[4];
    if constexpr (USE_P) {
#pragma unroll
        for (int g = 0; g < 4; ++g) pt[g] = Pb[g * U2 + u];
    }

#pragma unroll 1
    for (int t = 0; t < len; ++t) {
        float ptn[4];
        if constexpr (USE_P) {
            // prefetch next step's P early so the VMEM latency overlaps the FMAs
            const int tn = (t + 1 < len) ? (t + 1) : (len - 1);
            const float* Ptn = Pb + (size_t)tn * G2;
#pragma unroll
            for (int g = 0; g < 4; ++g) ptn[g] = Ptn[g * U2 + u];
        }

        float z[4];
        if constexpr (USE_P) {
#pragma unroll
            for (int g = 0; g < 4; ++g) z[g] = pt[g];
        } else {
#pragma unroll
            for (int g = 0; g < 4; ++g) z[g] = bz[g];
            const float* Ft = Pb + (size_t)t * U1;
#pragma unroll
            for (int k = 0; k < U1; ++k) {
                const float fk = Ft[k];   // uniform address -> s_load
#pragma unroll
                for (int g = 0; g < 4; ++g) z[g] += fk * wx[g][k];
            }
        }

#pragma unroll
        for (int k = 0; k < U2; ++k) {
            const float hk = hs[p][k];    // broadcast LDS read
#pragma unroll
            for (int g = 0; g < 4; ++g) z[g] += hk * wu[g][k];
        }

        const float ig = sigmoidf_(z[0]);
        const float fg = sigmoidf_(z[1]);
        const float gg = tanhf_fast(z[2]);
        const float og = sigmoidf_(z[3]);
        cu = fg * cu + ig * gg;
        hu = og * tanhf_fast(cu);

        if (lane < U2) hs[p ^ 1][lane] = hu;   // write OTHER buffer: no WAR hazard
        __syncthreads();                        // one barrier/step (RAW)
        p ^= 1;

        if constexpr (USE_P) {
#pragma unroll
            for (int g = 0; g < 4; ++g) pt[g] = ptn[g];
        }
    }

    if (lane == 0) {
        float acc = bd[0];
#pragma unroll
        for (int k = 0; k < U2; ++k) acc += hs[p][k] * Wd[k];
        out[b] = sigmoidf_(acc);
    }
}

extern "C" void kernel_launch(void* const* d_in, const int* in_sizes, int n_in,
                              void* d_out, int out_size, void* d_ws, size_t ws_size,
                              hipStream_t stream) {
    const float* x       = (const float*)d_in[0];
    const int*   lengths = (const int*)  d_in[1];
    const float* Wi      = (const float*)d_in[2];
    const float* Ui      = (const float*)d_in[3];
    const float* bi      = (const float*)d_in[4];
    const float* Wo      = (const float*)d_in[5];
    const float* Uo      = (const float*)d_in[6];
    const float* bo      = (const float*)d_in[7];
    const float* Wd      = (const float*)d_in[8];
    const float* bd      = (const float*)d_in[9];
    float* out = (float*)d_out;

    const size_t P_BYTES = (size_t)B * T * G2 * sizeof(float);   // 25.2 MB

    if (ws_size >= P_BYTES) {
        float* P = (float*)d_ws;
        inner_kernel<true><<<dim3(B * T / 256), dim3(256), 0, stream>>>(
            x, lengths, Wi, Ui, bi, Wo, bo, P);
        outer_kernel<true><<<dim3(B), dim3(64), 0, stream>>>(
            P, lengths, Wo, Uo, bo, Wd, bd, out);
    } else {
        float* F = (float*)d_ws;   // 8.4 MB feats fallback
        inner_kernel<false><<<dim3(B * T / 256), dim3(256), 0, stream>>>(
            x, lengths, Wi, Ui, bi, Wo, bo, F);
        outer_kernel<false><<<dim3(B), dim3(64), 0, stream>>>(
            F, lengths, Wo, Uo, bo, Wd, bd, out);
    }
}

// Round 2
// 477.649 us; speedup vs baseline: 1.0026x; 1.0026x over previous
//
#include <hip/hip_runtime.h>

#define B_  256
#define T_  256
#define S_  20
#define U1  32
#define G1  128   // 4*U1
#define U2  24
#define G2  96    // 4*U2

__device__ __forceinline__ float fast_rcp(float x) { return __builtin_amdgcn_rcpf(x); }
__device__ __forceinline__ float sigmoidf_(float x) { return fast_rcp(1.0f + __expf(-x)); }
// tanh(x) = 1 - 2/(1+e^{2x}); saturates correctly at +-1 for large |x|
__device__ __forceinline__ float tanhf_fast(float x) { return 1.0f - 2.0f * fast_rcp(1.0f + __expf(2.0f * x)); }

// Inner LSTM, one thread per (b,t) row, gate-phase structure:
//  - per phase only z[32] live (peak regs ~150, no spills; V1 spilled z[128] -> 12 GB scratch traffic)
//  - h kept in LDS as a per-lane indexable array (stride 33 = conflict-free; each lane
//    reads only its own h, so NO barriers; 128 ds_read/step << 4096 FMA/step)
//  - weights via wave-uniform s_load_dwordx16 (original row-major layout is already contiguous per phase)
template <bool WRITE_P>
__global__ __launch_bounds__(64, 2) void inner_kernel(
    const float* __restrict__ x,        // [B*T*S]
    const int*   __restrict__ lengths,  // [B]
    const float* __restrict__ Wi,       // [G1]
    const float* __restrict__ Ui,       // [U1*G1]
    const float* __restrict__ bi,       // [G1]
    const float* __restrict__ Wo,       // [U1*G2]
    const float* __restrict__ bo,       // [G2]
    float* __restrict__ outbuf)         // P [B*T*G2] or feats [B*T*U1]
{
    __shared__ float ldsH[64 * 33];
    const int lane = threadIdx.x;
    const int r = blockIdx.x * 64 + lane;   // row = b*T + t
    const int t = r & (T_ - 1);
    const int b = r >> 8;
    if (t >= lengths[b]) return;            // masked rows: never read downstream
    float* hL = ldsH + lane * 33;

    const float* xp = x + (size_t)r * S_;
    float c[U1];
#pragma unroll
    for (int j = 0; j < U1; ++j) c[j] = 0.0f;

    float xv = xp[0];
#pragma unroll 1
    for (int s = 0; s < S_; ++s) {
        const int sn = (s + 1 < S_) ? s + 1 : S_ - 1;
        const float xn = xp[sn];            // prefetch next step's x (latency hidden)
        float ga[U1], ia[U1];

        // ---- phase G (gate idx 2): ga = tanh(z)
        {
            float z[U1];
#pragma unroll
            for (int j = 0; j < U1; ++j) z[j] = bi[2 * U1 + j] + xv * Wi[2 * U1 + j];
            if (s > 0) {
#pragma unroll 2
                for (int k = 0; k < U1; ++k) {
                    const float hk = hL[k];
                    const float* Ur = Ui + k * G1 + 2 * U1;
#pragma unroll
                    for (int j = 0; j < U1; ++j) z[j] += hk * Ur[j];
                }
            }
#pragma unroll
            for (int j = 0; j < U1; ++j) ga[j] = tanhf_fast(z[j]);
        }
        // ---- phase I (gate idx 0): ia = sigmoid(z)
        {
            float z[U1];
#pragma unroll
            for (int j = 0; j < U1; ++j) z[j] = bi[j] + xv * Wi[j];
            if (s > 0) {
#pragma unroll 2
                for (int k = 0; k < U1; ++k) {
                    const float hk = hL[k];
                    const float* Ur = Ui + k * G1;
#pragma unroll
                    for (int j = 0; j < U1; ++j) z[j] += hk * Ur[j];
                }
            }
#pragma unroll
            for (int j = 0; j < U1; ++j) ia[j] = sigmoidf_(z[j]);
        }
        // ---- phase F (gate idx 1): c = sigmoid(z)*c + ia*ga
        {
            float z[U1];
#pragma unroll
            for (int j = 0; j < U1; ++j) z[j] = bi[U1 + j] + xv * Wi[U1 + j];
            if (s > 0) {
#pragma unroll 2
                for (int k = 0; k < U1; ++k) {
                    const float hk = hL[k];
                    const float* Ur = Ui + k * G1 + U1;
#pragma unroll
                    for (int j = 0; j < U1; ++j) z[j] += hk * Ur[j];
                }
            }
#pragma unroll
            for (int j = 0; j < U1; ++j) c[j] = sigmoidf_(z[j]) * c[j] + ia[j] * ga[j];
        }
        // ---- phase O (gate idx 3): h = sigmoid(z)*tanh(c) -> LDS
        {
            float z[U1];
#pragma unroll
            for (int j = 0; j < U1; ++j) z[j] = bi[3 * U1 + j] + xv * Wi[3 * U1 + j];
            if (s > 0) {
#pragma unroll 2
                for (int k = 0; k < U1; ++k) {
                    const float hk = hL[k];
                    const float* Ur = Ui + k * G1 + 3 * U1;
#pragma unroll
                    for (int j = 0; j < U1; ++j) z[j] += hk * Ur[j];
                }
            }
#pragma unroll
            for (int j = 0; j < U1; ++j) hL[j] = sigmoidf_(z[j]) * tanhf_fast(c[j]);
        }
        xv = xn;
    }

    if constexpr (WRITE_P) {
        // P row = bo + h @ Wo (outer LSTM input matmul folded in here, 1024 waves of parallelism)
        float p[G2];
#pragma unroll
        for (int j = 0; j < G2; ++j) p[j] = bo[j];
#pragma unroll 2
        for (int k = 0; k < U1; ++k) {
            const float hk = hL[k];
            const float* Wr = Wo + k * G2;
#pragma unroll
            for (int j = 0; j < G2; ++j) p[j] += hk * Wr[j];
        }
        float4* Pp = (float4*)(outbuf + (size_t)r * G2);
#pragma unroll
        for (int j = 0; j < G2 / 4; ++j)
            Pp[j] = make_float4(p[4 * j], p[4 * j + 1], p[4 * j + 2], p[4 * j + 3]);
    } else {
        float4* Fp = (float4*)(outbuf + (size_t)r * U1);
#pragma unroll
        for (int j = 0; j < U1 / 4; ++j)
            Fp[j] = make_float4(hL[4 * j], hL[4 * j + 1], hL[4 * j + 2], hL[4 * j + 3]);
    }
}

// Outer LSTM + head: 1 wave per sequence. Lane u<24 owns unit u (all 4 gates local).
// h broadcast via __shfl (same-wave ds_bpermute): no LDS, no barrier -> shorter
// per-step latency chain than the V1 LDS double-buffer + __syncthreads.
template <bool USE_P>
__global__ __launch_bounds__(64, 1) void outer_kernel(
    const float* __restrict__ buf,      // P [B*T*G2] or feats [B*T*U1]
    const int*   __restrict__ lengths,  // [B]
    const float* __restrict__ Wo,       // (only if !USE_P)
    const float* __restrict__ Uo,       // [U2*G2]
    const float* __restrict__ bo,       // (only if !USE_P)
    const float* __restrict__ Wd,       // [U2]
    const float* __restrict__ bd,       // [1]
    float* __restrict__ out)            // [B]
{
    const int b = blockIdx.x;
    const int lane = threadIdx.x;
    const int u = (lane < U2) ? lane : 0;

    float wu[4][U2];
#pragma unroll
    for (int g = 0; g < 4; ++g)
#pragma unroll
        for (int k = 0; k < U2; ++k)
            wu[g][k] = Uo[k * G2 + g * U2 + u];

    float wx[4][U1];
    float bz[4];
    if constexpr (!USE_P) {
#pragma unroll
        for (int g = 0; g < 4; ++g) {
            bz[g] = bo[g * U2 + u];
#pragma unroll
            for (int k = 0; k < U1; ++k)
                wx[g][k] = Wo[k * G2 + g * U2 + u];
        }
    }

    const int len = lengths[b];              // >= 1 by construction
    const int rowstride = USE_P ? G2 : U1;
    const float* Pb = buf + (size_t)b * T_ * rowstride;

    float cu = 0.0f, hu = 0.0f;
    float pt[4];
    if constexpr (USE_P) {
#pragma unroll
        for (int g = 0; g < 4; ++g) pt[g] = Pb[g * U2 + u];
    }

#pragma unroll 1
    for (int t = 0; t < len; ++t) {
        float ptn[4];
        if constexpr (USE_P) {
            const int tn = (t + 1 < len) ? (t + 1) : (len - 1);
            const float* Ptn = Pb + (size_t)tn * G2;
#pragma unroll
            for (int g = 0; g < 4; ++g) ptn[g] = Ptn[g * U2 + u];
        }

        float z[4];
        if constexpr (USE_P) {
#pragma unroll
            for (int g = 0; g < 4; ++g) z[g] = pt[g];
        } else {
#pragma unroll
            for (int g = 0; g < 4; ++g) z[g] = bz[g];
            const float* Ft = Pb + (size_t)t * U1;
#pragma unroll
            for (int k = 0; k < U1; ++k) {
                const float fk = Ft[k];      // uniform address -> s_load
#pragma unroll
                for (int g = 0; g < 4; ++g) z[g] += fk * wx[g][k];
            }
        }

        if (t > 0) {                         // uniform branch; h==0 at t==0
            float hk[U2];
#pragma unroll
            for (int k = 0; k < U2; ++k) hk[k] = __shfl(hu, k);   // broadcast, no barrier
#pragma unroll
            for (int k = 0; k < U2; ++k)
#pragma unroll
                for (int g = 0; g < 4; ++g) z[g] += hk[k] * wu[g][k];
        }

        const float ig = sigmoidf_(z[0]);
        const float fg = sigmoidf_(z[1]);
        const float gg = tanhf_fast(z[2]);
        const float og = sigmoidf_(z[3]);
        cu = fg * cu + ig * gg;
        hu = og * tanhf_fast(cu);

        if constexpr (USE_P) {
#pragma unroll
            for (int g = 0; g < 4; ++g) pt[g] = ptn[g];
        }
    }

    // dense sigmoid head: gather final h (convergent shuffles), lane 0 writes
    float acc = bd[0];
#pragma unroll
    for (int k = 0; k < U2; ++k) acc += __shfl(hu, k) * Wd[k];
    if (lane == 0) out[b] = sigmoidf_(acc);
}

extern "C" void kernel_launch(void* const* d_in, const int* in_sizes, int n_in,
                              void* d_out, int out_size, void* d_ws, size_t ws_size,
                              hipStream_t stream) {
    const float* x       = (const float*)d_in[0];
    const int*   lengths = (const int*)  d_in[1];
    const float* Wi      = (const float*)d_in[2];
    const float* Ui      = (const float*)d_in[3];
    const float* bi      = (const float*)d_in[4];
    const float* Wo      = (const float*)d_in[5];
    const float* Uo      = (const float*)d_in[6];
    const float* bo      = (const float*)d_in[7];
    const float* Wd      = (const float*)d_in[8];
    const float* bd      = (const float*)d_in[9];
    float* out = (float*)d_out;

    const size_t P_BYTES = (size_t)B_ * T_ * G2 * sizeof(float);   // 25.2 MB

    if (ws_size >= P_BYTES) {
        float* P = (float*)d_ws;
        inner_kernel<true><<<dim3(B_ * T_ / 64), dim3(64), 0, stream>>>(
            x, lengths, Wi, Ui, bi, Wo, bo, P);
        outer_kernel<true><<<dim3(B_), dim3(64), 0, stream>>>(
            P, lengths, Wo, Uo, bo, Wd, bd, out);
    } else {
        float* F = (float*)d_ws;   // 8.4 MB feats fallback
        inner_kernel<false><<<dim3(B_ * T_ / 64), dim3(64), 0, stream>>>(
            x, lengths, Wi, Ui, bi, Wo, bo, F);
        outer_kernel<false><<<dim3(B_), dim3(64), 0, stream>>>(
            F, lengths, Wo, Uo, bo, Wd, bd, out);
    }
}